// Round 2
// baseline (1596.917 us; speedup 1.0000x reference)
//
#include <hip/hip_runtime.h>

static constexpr int kBS = 16;
static constexpr int kNA = 256;
static constexpr int kHW = 1024;
static constexpr int kC  = 512;
static constexpr int kH3 = 1536;

// ---------------------------------------------------------------------------
// Generic 128x128x16 fp32 tile GEMM.
//   C[m,n] = act(scale * sum_k opA[m,k]*opB[k,n] + bias[n])
// TA=true : A stored row-major [M,K] (lda = row stride)  -> transpose into LDS
// TA=false: A stored [K,M] (lda = row stride of K-major) -> direct into LDS
// TB=true : B stored row-major [N,K] -> transpose into LDS
// TB=false: B stored [K,N] -> direct into LDS
// grid.z = batch with strides sA/sB/sC (elements).
// Requires M%128==0, N%128==0, K%16==0 (all shapes here satisfy this).
// ---------------------------------------------------------------------------
template<bool TA, bool TB, bool BIAS, bool RELU>
__global__ __launch_bounds__(256, 4)
void gemm128(const float* __restrict__ A, const float* __restrict__ B,
             const float* __restrict__ bias, float* __restrict__ C,
             int M, int N, int K, int lda, int ldb, int ldc,
             long sA, long sB, long sC, float scale)
{
  A += (long)blockIdx.z * sA;
  B += (long)blockIdx.z * sB;
  C += (long)blockIdx.z * sC;

  // +4 pad keeps row stride (132 floats = 528B) 16B-aligned for b128 reads
  __shared__ float As[16][132];
  __shared__ float Bs[16][132];

  const int tid = threadIdx.x;
  const int bm = blockIdx.x * 128;
  const int bn = blockIdx.y * 128;
  const int tx = tid & 15;   // -> n
  const int ty = tid >> 4;   // -> m

  float acc[8][8];
#pragma unroll
  for (int i = 0; i < 8; ++i)
#pragma unroll
    for (int j = 0; j < 8; ++j) acc[i][j] = 0.f;

  for (int k0 = 0; k0 < K; k0 += 16) {
    if (TA) {
      const int m = tid >> 1, kk = (tid & 1) * 8;
      const float* ap = A + (size_t)(bm + m) * lda + (k0 + kk);
      float4 x = *(const float4*)ap;
      float4 y = *(const float4*)(ap + 4);
      As[kk+0][m] = x.x; As[kk+1][m] = x.y; As[kk+2][m] = x.z; As[kk+3][m] = x.w;
      As[kk+4][m] = y.x; As[kk+5][m] = y.y; As[kk+6][m] = y.z; As[kk+7][m] = y.w;
    } else {
      const int kk = tid >> 4, m = (tid & 15) * 8;
      const float* ap = A + (size_t)(k0 + kk) * lda + (bm + m);
      *(float4*)&As[kk][m]     = *(const float4*)ap;
      *(float4*)&As[kk][m + 4] = *(const float4*)(ap + 4);
    }
    if (TB) {
      const int n = tid >> 1, kk = (tid & 1) * 8;
      const float* bp = B + (size_t)(bn + n) * ldb + (k0 + kk);
      float4 x = *(const float4*)bp;
      float4 y = *(const float4*)(bp + 4);
      Bs[kk+0][n] = x.x; Bs[kk+1][n] = x.y; Bs[kk+2][n] = x.z; Bs[kk+3][n] = x.w;
      Bs[kk+4][n] = y.x; Bs[kk+5][n] = y.y; Bs[kk+6][n] = y.z; Bs[kk+7][n] = y.w;
    } else {
      const int kk = tid >> 4, n = (tid & 15) * 8;
      const float* bp = B + (size_t)(k0 + kk) * ldb + (bn + n);
      *(float4*)&Bs[kk][n]     = *(const float4*)bp;
      *(float4*)&Bs[kk][n + 4] = *(const float4*)(bp + 4);
    }
    __syncthreads();
#pragma unroll
    for (int kk = 0; kk < 16; ++kk) {
      float4 a0 = *(const float4*)&As[kk][ty * 8];
      float4 a1 = *(const float4*)&As[kk][ty * 8 + 4];
      float4 b0 = *(const float4*)&Bs[kk][tx * 4];        // 2-way alias: free
      float4 b1 = *(const float4*)&Bs[kk][tx * 4 + 64];   // 2-way alias: free
      float ar[8] = {a0.x,a0.y,a0.z,a0.w,a1.x,a1.y,a1.z,a1.w};
      float br[8] = {b0.x,b0.y,b0.z,b0.w,b1.x,b1.y,b1.z,b1.w};
#pragma unroll
      for (int i = 0; i < 8; ++i)
#pragma unroll
        for (int j = 0; j < 8; ++j)
          acc[i][j] = fmaf(ar[i], br[j], acc[i][j]);
    }
    __syncthreads();
  }

#pragma unroll
  for (int i = 0; i < 8; ++i) {
    const int m = bm + ty * 8 + i;
#pragma unroll
    for (int h = 0; h < 2; ++h) {
      const int n = bn + h * 64 + tx * 4;
      float4 o;
      o.x = acc[i][h*4+0] * scale; o.y = acc[i][h*4+1] * scale;
      o.z = acc[i][h*4+2] * scale; o.w = acc[i][h*4+3] * scale;
      if (BIAS) {
        const float4 bb = *(const float4*)(bias + n);
        o.x += bb.x; o.y += bb.y; o.z += bb.z; o.w += bb.w;
      }
      if (RELU) {
        o.x = fmaxf(o.x, 0.f); o.y = fmaxf(o.y, 0.f);
        o.z = fmaxf(o.z, 0.f); o.w = fmaxf(o.w, 0.f);
      }
      *(float4*)(C + (size_t)m * ldc + n) = o;
    }
  }
}

// ---------------------------------------------------------------------------
// Row argmax over rows of length 256 (first-max tie rule, matches np.argmax).
// One wave per row.
// ---------------------------------------------------------------------------
__global__ __launch_bounds__(64)
void row_argmax(const float* __restrict__ X, int* __restrict__ out)
{
  const int row = blockIdx.x;
  const float* xr = X + (size_t)row * 256;
  const int lane = threadIdx.x;
  float best = -3.0e38f;
  int bi = 0;
#pragma unroll
  for (int t = 0; t < 4; ++t) {
    const int a = lane + (t << 6);
    const float x = xr[a];
    if (x > best) { best = x; bi = a; }   // strictly greater keeps earliest
  }
#pragma unroll
  for (int off = 32; off >= 1; off >>= 1) {
    const float ov = __shfl_xor(best, off);
    const int   oi = __shfl_xor(bi, off);
    if (ov > best || (ov == best && oi < bi)) { best = ov; bi = oi; }
  }
  if (lane == 0) out[row] = bi;
}

// ---------------------------------------------------------------------------
// In-place masked softmax over rows of length 1024.
// L[row, j] += (bidx[b,j]==aidx[b,i]) ? 0 : -1e6, then softmax over j.
// One 256-thread block per row (row = b*1024 + i).
// ---------------------------------------------------------------------------
__global__ __launch_bounds__(256)
void softmax_mask(float* __restrict__ L, const int* __restrict__ aidx,
                  const int* __restrict__ bidx)
{
  __shared__ float red[4];
  const int row = blockIdx.x;
  const int b = row >> 10;
  float* Lr = L + (size_t)row * 1024;
  const int* bj = bidx + (b << 10);
  const int ai = aidx[row];
  const int tid = threadIdx.x;

  float v[4];
  float mx = -3.0e38f;
#pragma unroll
  for (int t = 0; t < 4; ++t) {
    const int j = tid + (t << 8);
    float x = Lr[j];
    if (bj[j] != ai) x -= 1e6f;
    v[t] = x;
    mx = fmaxf(mx, x);
  }
#pragma unroll
  for (int off = 32; off >= 1; off >>= 1) mx = fmaxf(mx, __shfl_xor(mx, off));
  if ((tid & 63) == 0) red[tid >> 6] = mx;
  __syncthreads();
  mx = fmaxf(fmaxf(red[0], red[1]), fmaxf(red[2], red[3]));
  __syncthreads();

  float e[4];
  float s = 0.f;
#pragma unroll
  for (int t = 0; t < 4; ++t) { e[t] = expf(v[t] - mx); s += e[t]; }
#pragma unroll
  for (int off = 32; off >= 1; off >>= 1) s += __shfl_xor(s, off);
  if ((tid & 63) == 0) red[tid >> 6] = s;
  __syncthreads();
  s = (red[0] + red[1]) + (red[2] + red[3]);
  const float inv = 1.f / s;
#pragma unroll
  for (int t = 0; t < 4; ++t) Lr[tid + (t << 8)] = e[t] * inv;
}

// ---------------------------------------------------------------------------
extern "C" void kernel_launch(void* const* d_in, const int* in_sizes, int n_in,
                              void* d_out, int out_size, void* d_ws, size_t ws_size,
                              hipStream_t stream)
{
  (void)in_sizes; (void)n_in; (void)out_size; (void)ws_size;

  const float* tok  = (const float*)d_in[0];
  const float* supp = (const float*)d_in[1];
  const float* qry  = (const float*)d_in[2];
  const float* W_qa = (const float*)d_in[3];
  const float* b_qa = (const float*)d_in[4];
  const float* W_ks = (const float*)d_in[5];
  const float* b_ks = (const float*)d_in[6];
  const float* W_ka = (const float*)d_in[7];
  const float* b_ka = (const float*)d_in[8];
  const float* W_vs = (const float*)d_in[9];
  const float* b_vs = (const float*)d_in[10];
  const float* W_f1 = (const float*)d_in[11];
  const float* b_f1 = (const float*)d_in[12];
  const float* W_f2 = (const float*)d_in[13];
  const float* b_f2 = (const float*)d_in[14];
  float* out = (float*)d_out;
  float* ws  = (float*)d_ws;

  // workspace layout (fp32 elements); logits & ffn-mid alias dead regions
  float* qa = ws;                                  //  2,097,152
  float* ka = qa + (size_t)kBS * kNA * kC;         //  2,097,152
  float* ks = ka + (size_t)kBS * kNA * kC;         //  8,388,608
  float* qq = ks + (size_t)kBS * kHW * kC;         //  8,388,608
  float* vs = qq + (size_t)kBS * kHW * kC;         //  8,388,608   (ws+20,971,520)
  float* sa = vs + (size_t)kBS * kHW * kC;         //  4,194,304   SA_T[b,i,a]
  float* qt = sa + (size_t)kBS * kHW * kNA;        //  4,194,304   QA[b,j,a]
  int*  aidx = (int*)(qt + (size_t)kBS * kHW * kNA);
  int*  bidx = aidx + kBS * kHW;
  float* Lg  = ws;   // logits [b,i,j]: 16,777,216 <= dead qa..qq region (20,971,520)
  float* mid = ws;   // ffn mid: 25,165,824 <= dead region before sa (29,360,128)

  const dim3 blk(256);

  // --- projections (flat 2D, weights shared over batch) ---
  gemm128<true,false,true,false><<<dim3(32,4,1),  blk, 0, stream>>>(tok,  W_qa, b_qa, qa, 4096, 512, 512, 512, 512, 512, 0,0,0, 1.f);
  gemm128<true,false,true,false><<<dim3(32,4,1),  blk, 0, stream>>>(tok,  W_ka, b_ka, ka, 4096, 512, 512, 512, 512, 512, 0,0,0, 1.f);
  gemm128<true,false,true,false><<<dim3(128,4,1), blk, 0, stream>>>(supp, W_ks, b_ks, ks, 16384,512, 512, 512, 512, 512, 0,0,0, 1.f);
  gemm128<true,false,true,false><<<dim3(128,4,1), blk, 0, stream>>>(qry,  W_qa, b_qa, qq, 16384,512, 512, 512, 512, 512, 0,0,0, 1.f);
  gemm128<true,false,true,false><<<dim3(128,4,1), blk, 0, stream>>>(supp, W_vs, b_vs, vs, 16384,512, 512, 512, 512, 512, 0,0,0, 1.f);

  // --- scores: SA_T = ks @ qa^T / 8 ; QA = qq @ ka^T / 8 (batched NT) ---
  gemm128<true,true,false,false><<<dim3(8,2,16), blk, 0, stream>>>(ks, qa, nullptr, sa, 1024, 256, 512, 512, 512, 256,
      (long)kHW*kC, (long)kNA*kC, (long)kHW*kNA, 0.125f);
  gemm128<true,true,false,false><<<dim3(8,2,16), blk, 0, stream>>>(qq, ka, nullptr, qt, 1024, 256, 512, 512, 512, 256,
      (long)kHW*kC, (long)kNA*kC, (long)kHW*kNA, 0.125f);

  // --- argmaxes ---
  row_argmax<<<dim3(kBS * kHW), dim3(64), 0, stream>>>(sa, aidx);
  row_argmax<<<dim3(kBS * kHW), dim3(64), 0, stream>>>(qt, bidx);

  // --- logits = SA_T @ QA^T (batched NT) ---
  gemm128<true,true,false,false><<<dim3(8,8,16), blk, 0, stream>>>(sa, qt, nullptr, Lg, 1024, 1024, 256, 256, 256, 1024,
      (long)kHW*kNA, (long)kHW*kNA, (long)kHW*kHW, 1.f);

  // --- masked softmax in place ---
  softmax_mask<<<dim3(kBS * kHW), dim3(256), 0, stream>>>(Lg, aidx, bidx);

  // --- dec = P^T @ vs (batched TN) -> staged in d_out ---
  gemm128<false,false,false,false><<<dim3(8,4,16), blk, 0, stream>>>(Lg, vs, nullptr, out, 1024, 512, 1024, 1024, 512, 512,
      (long)kHW*kHW, (long)kHW*kC, (long)kHW*kC, 1.f);

  // --- FFN: mid = relu(dec @ W_f1 + b1); out = mid @ W_f2 + b2 ---
  gemm128<true,false,true,true ><<<dim3(128,12,1), blk, 0, stream>>>(out, W_f1, b_f1, mid, 16384, 1536, 512, 512, 1536, 1536, 0,0,0, 1.f);
  gemm128<true,false,true,false><<<dim3(128,4,1),  blk, 0, stream>>>(mid, W_f2, b_f2, out, 16384, 512, 1536, 1536, 512, 512, 0,0,0, 1.f);
}

// Round 3
// 732.609 us; speedup vs baseline: 2.1798x; 2.1798x over previous
//
#include <hip/hip_runtime.h>

typedef float          f32x4  __attribute__((ext_vector_type(4)));
typedef short          bf16x8 __attribute__((ext_vector_type(8)));
typedef unsigned short u16x4  __attribute__((ext_vector_type(4)));

static constexpr int kBS = 16;
static constexpr int kNA = 256;
static constexpr int kHW = 1024;
static constexpr int kC  = 512;

__device__ __forceinline__ unsigned short f2bf(float x) {
  union { float f; unsigned int u; } v; v.f = x;
  unsigned int r = v.u + 0x7fffu + ((v.u >> 16) & 1u);
  return (unsigned short)(r >> 16);
}
__device__ __forceinline__ float bf2f(unsigned short h) {
  union { unsigned int u; float f; } v; v.u = ((unsigned int)h) << 16;
  return v.f;
}

// ---------------------------------------------------------------------------
// split kernels: fp32 -> NP bf16 planes (a = a0 + a1 [+ a2] with RNE residuals)
// ---------------------------------------------------------------------------
template<int NP>
__global__ __launch_bounds__(256)
void split_act(const f32x4* __restrict__ X, u16x4* __restrict__ P0,
               u16x4* __restrict__ P1, u16x4* __restrict__ P2, int n4)
{
  int i = blockIdx.x * 256 + threadIdx.x;
  if (i >= n4) return;
  f32x4 x = X[i];
  u16x4 s0, s1, s2;
#pragma unroll
  for (int u = 0; u < 4; ++u) {
    unsigned short h0 = f2bf(x[u]); float r1 = x[u] - bf2f(h0);
    unsigned short h1 = f2bf(r1);
    s0[u] = h0; s1[u] = h1;
    if (NP == 3) s2[u] = f2bf(r1 - bf2f(h1));
  }
  P0[i] = s0;
  if (NP >= 2) P1[i] = s1;
  if (NP == 3) P2[i] = s2;
}

// W [K][N] fp32 -> NP bf16 planes of W^T [N][K]
template<int NP>
__global__ __launch_bounds__(256)
void split_wT(const float* __restrict__ Wm, unsigned short* __restrict__ T0,
              unsigned short* __restrict__ T1, unsigned short* __restrict__ T2,
              int K, int N)
{
  __shared__ float ts[32][33];
  const int k0 = blockIdx.x * 32, n0 = blockIdx.y * 32;
  const int tx = threadIdx.x, ty = threadIdx.y;   // 32 x 8
#pragma unroll
  for (int r = 0; r < 4; ++r)
    ts[ty + r * 8][tx] = Wm[(size_t)(k0 + ty + r * 8) * N + n0 + tx];
  __syncthreads();
#pragma unroll
  for (int r = 0; r < 4; ++r) {
    const int n = ty + r * 8;
    const float x = ts[tx][n];
    const size_t off = (size_t)(n0 + n) * K + k0 + tx;
    unsigned short h0 = f2bf(x); float r1 = x - bf2f(h0);
    unsigned short h1 = f2bf(r1);
    T0[off] = h0;
    if (NP >= 2) T1[off] = h1;
    if (NP == 3) T2[off] = f2bf(r1 - bf2f(h1));
  }
}

// ---------------------------------------------------------------------------
// MFMA GEMM: 128x128 tile, 4 waves (2x2), 16x16x32 bf16, BK=32, double-buffered
// LDS via global_load_lds(16B) with XOR-swizzle (pre-swizzled global source).
// A planes: [M][K] bf16; B planes: [N][K] bf16 (i.e. B^T storage).
// NPASS pairs (a,b): (0,0),(0,1),(1,0),(1,1),(0,2),(2,0) accumulated in fp32.
// OUTM: 0=f32, 1=bf16, 2=bf16 transposed ([N][M], ldc=M), 3=f32+2 planes,
//       4=3 planes.
// ---------------------------------------------------------------------------
#define PASS_PTRS(p, pA, pB)            \
  switch (p) {                          \
    default: pA = Ap0; pB = Bp0; break; \
    case 1:  pA = Ap0; pB = Bp1; break; \
    case 2:  pA = Ap1; pB = Bp0; break; \
    case 3:  pA = Ap1; pB = Bp1; break; \
    case 4:  pA = Ap0; pB = Bp2; break; \
    case 5:  pA = Ap2; pB = Bp0; break; \
  }

__device__ __forceinline__ void stage_pair(const unsigned short* gA,
                                           const unsigned short* gB, int K,
                                           unsigned short* lA, unsigned short* lB,
                                           int wv, int lane)
{
#pragma unroll
  for (int i = 0; i < 2; ++i) {
    const int s   = wv * 128 + i * 64 + lane;
    const int row = s >> 2;
    const int gc  = ((s & 3) ^ ((row >> 1) & 3)) * 8;   // inverse(=same) swizzle
    __builtin_amdgcn_global_load_lds(
        (const __attribute__((address_space(1))) void*)(gA + (size_t)row * K + gc),
        (__attribute__((address_space(3))) void*)(lA + ((wv * 128 + i * 64) << 3)),
        16, 0, 0);
    __builtin_amdgcn_global_load_lds(
        (const __attribute__((address_space(1))) void*)(gB + (size_t)row * K + gc),
        (__attribute__((address_space(3))) void*)(lB + ((wv * 128 + i * 64) << 3)),
        16, 0, 0);
  }
}

template<int NPASS, int OUTM, bool BIAS, bool RELU>
__global__ __launch_bounds__(256)
void gmfma(const unsigned short* __restrict__ A0, const unsigned short* __restrict__ A1,
           const unsigned short* __restrict__ A2,
           const unsigned short* __restrict__ B0, const unsigned short* __restrict__ B1,
           const unsigned short* __restrict__ B2,
           const float* __restrict__ bias,
           float* __restrict__ Cf, unsigned short* __restrict__ O0,
           unsigned short* __restrict__ O1, unsigned short* __restrict__ O2,
           int K, int ldc, long sA, long sB, long sC, float scale)
{
  __shared__ alignas(16) unsigned short lsA[2][4096];
  __shared__ alignas(16) unsigned short lsB[2][4096];

  const int tid  = threadIdx.x;
  const int wv   = tid >> 6, lane = tid & 63;
  const int wr   = wv >> 1,  wc   = wv & 1;
  const int cr   = lane & 15, cg  = lane >> 4;
  const int bm   = blockIdx.x * 128, bn = blockIdx.y * 128;

  const size_t zA = (size_t)blockIdx.z * (size_t)sA;
  const size_t zB = (size_t)blockIdx.z * (size_t)sB;
  const size_t zC = (size_t)blockIdx.z * (size_t)sC;
  const unsigned short *Ap0 = A0 + zA, *Ap1 = A1 + zA, *Ap2 = A2 + zA;
  const unsigned short *Bp0 = B0 + zB, *Bp1 = B1 + zB, *Bp2 = B2 + zB;

  f32x4 acc[4][4];
#pragma unroll
  for (int i = 0; i < 4; ++i)
#pragma unroll
    for (int j = 0; j < 4; ++j) {
      acc[i][j][0] = 0.f; acc[i][j][1] = 0.f; acc[i][j][2] = 0.f; acc[i][j][3] = 0.f;
    }

  const int nt = K >> 5;
  const int total = NPASS * nt;
  {
    const unsigned short *pA, *pB; const int p0 = 0;
    PASS_PTRS(p0, pA, pB);
    stage_pair(pA + (size_t)bm * K, pB + (size_t)bn * K, K, lsA[0], lsB[0], wv, lane);
  }
  for (int t = 0; t < total; ++t) {
    __syncthreads();                     // drains staging of buf[t&1]
    const int tn = t + 1;
    if (tn < total) {
      const int pn = tn / nt, kn = tn - pn * nt;
      const unsigned short *pA, *pB;
      PASS_PTRS(pn, pA, pB);
      stage_pair(pA + (size_t)bm * K + kn * 32, pB + (size_t)bn * K + kn * 32, K,
                 lsA[tn & 1], lsB[tn & 1], wv, lane);
    }
    const unsigned short* lA = lsA[t & 1];
    const unsigned short* lB = lsB[t & 1];
    bf16x8 af[4], bf[4];
#pragma unroll
    for (int f = 0; f < 4; ++f) {
      const int ra = wr * 64 + f * 16 + cr;
      af[f] = *(const bf16x8*)&lA[(ra * 4 + (cg ^ ((ra >> 1) & 3))) * 8];
      const int rb = wc * 64 + f * 16 + cr;
      bf[f] = *(const bf16x8*)&lB[(rb * 4 + (cg ^ ((rb >> 1) & 3))) * 8];
    }
#pragma unroll
    for (int i = 0; i < 4; ++i)
#pragma unroll
      for (int j = 0; j < 4; ++j)
        acc[i][j] = __builtin_amdgcn_mfma_f32_16x16x32_bf16(af[i], bf[j], acc[i][j], 0, 0, 0);
  }

  // epilogue: C/D layout col = lane&15, row = 4*(lane>>4)+reg  [m89-verified]
  float* CfB = Cf + zC;
  unsigned short* O0B = O0 + zC;
  unsigned short* O1B = O1 + zC;
  unsigned short* O2B = O2 + zC;
#pragma unroll
  for (int fm = 0; fm < 4; ++fm) {
#pragma unroll
    for (int fn = 0; fn < 4; ++fn) {
      const int n  = bn + wc * 64 + fn * 16 + cr;
      const int m0 = bm + wr * 64 + fm * 16 + 4 * cg;
      float bv = 0.f;
      if (BIAS) bv = bias[n];
      f32x4 v = acc[fm][fn];
      if (OUTM == 2) {
        u16x4 o;
#pragma unroll
        for (int r = 0; r < 4; ++r) {
          float x = v[r] * scale + bv;
          if (RELU) x = fmaxf(x, 0.f);
          o[r] = f2bf(x);
        }
        *(u16x4*)(O0B + (size_t)n * ldc + m0) = o;
      } else {
#pragma unroll
        for (int r = 0; r < 4; ++r) {
          float x = v[r] * scale + bv;
          if (RELU) x = fmaxf(x, 0.f);
          const size_t off = (size_t)(m0 + r) * ldc + n;
          if (OUTM == 0) CfB[off] = x;
          else if (OUTM == 1) O0B[off] = f2bf(x);
          else {
            unsigned short h0 = f2bf(x); float r1 = x - bf2f(h0);
            unsigned short h1 = f2bf(r1);
            O0B[off] = h0; O1B[off] = h1;
            if (OUTM == 4) O2B[off] = f2bf(r1 - bf2f(h1));
            if (OUTM == 3) CfB[off] = x;
          }
        }
      }
    }
  }
}

// ---------------------------------------------------------------------------
// Row argmax over rows of length 256 (np.argmax first-max tie rule).
// ---------------------------------------------------------------------------
__global__ __launch_bounds__(64)
void row_argmax(const float* __restrict__ X, int* __restrict__ out)
{
  const int row = blockIdx.x;
  const float* xr = X + (size_t)row * 256;
  const int lane = threadIdx.x;
  float best = -3.0e38f;
  int bi = 0;
#pragma unroll
  for (int t = 0; t < 4; ++t) {
    const int a = lane + (t << 6);
    const float x = xr[a];
    if (x > best) { best = x; bi = a; }
  }
#pragma unroll
  for (int off = 32; off >= 1; off >>= 1) {
    const float ov = __shfl_xor(best, off);
    const int   oi = __shfl_xor(bi, off);
    if (ov > best || (ov == best && oi < bi)) { best = ov; bi = oi; }
  }
  if (lane == 0) out[row] = bi;
}

// ---------------------------------------------------------------------------
// Masked softmax over rows of length 1024, emits P^T[b][j][i] in bf16.
// Block: 16 rows (i) x 1024 cols (j); 256 threads = 16 rows x 16 lanes.
// ---------------------------------------------------------------------------
__global__ __launch_bounds__(256)
void softmax_T(const float* __restrict__ Lg, const int* __restrict__ aidx,
               const int* __restrict__ bidx, unsigned short* __restrict__ PT)
{
  __shared__ int bj[1024];
  __shared__ unsigned short tile[1024 * 17];
  const int tid = threadIdx.x;
  const int i0  = blockIdx.x * 16;
  const int b   = blockIdx.y;
  const int r   = tid >> 4;
  const int l16 = tid & 15;

  for (int j = tid; j < 1024; j += 256) bj[j] = bidx[(b << 10) + j];
  __syncthreads();

  const int row = (b << 10) + i0 + r;
  const int ai  = aidx[row];
  const float* Lr = Lg + (size_t)row * 1024;
  const int jb = l16 * 64;

  float x[64];
  float mx = -3.0e38f;
#pragma unroll
  for (int q = 0; q < 16; ++q) {
    f32x4 f = *(const f32x4*)(Lr + jb + (q << 2));
#pragma unroll
    for (int u = 0; u < 4; ++u) {
      const int j = jb + (q << 2) + u;
      float t = f[u];
      if (bj[j] != ai) t -= 1e6f;
      x[(q << 2) + u] = t;
      mx = fmaxf(mx, t);
    }
  }
#pragma unroll
  for (int off = 8; off >= 1; off >>= 1) mx = fmaxf(mx, __shfl_xor(mx, off));
  float s = 0.f;
#pragma unroll
  for (int k = 0; k < 64; ++k) { float e = expf(x[k] - mx); x[k] = e; s += e; }
#pragma unroll
  for (int off = 8; off >= 1; off >>= 1) s += __shfl_xor(s, off);
  const float inv = 1.f / s;

#pragma unroll
  for (int k = 0; k < 64; ++k)
    tile[(jb + k) * 17 + r] = f2bf(x[k] * inv);
  __syncthreads();

  for (int j = tid; j < 1024; j += 256) {
    const unsigned short* tp = &tile[j * 17];
    unsigned int w[8];
#pragma unroll
    for (int q = 0; q < 8; ++q)
      w[q] = (unsigned int)tp[2 * q] | ((unsigned int)tp[2 * q + 1] << 16);
    const size_t off = ((size_t)b << 20) + ((size_t)j << 10) + i0;
    unsigned int* dst = (unsigned int*)(PT + off);
    *(uint4*)dst       = make_uint4(w[0], w[1], w[2], w[3]);
    *((uint4*)dst + 1) = make_uint4(w[4], w[5], w[6], w[7]);
  }
}

// ---------------------------------------------------------------------------
extern "C" void kernel_launch(void* const* d_in, const int* in_sizes, int n_in,
                              void* d_out, int out_size, void* d_ws, size_t ws_size,
                              hipStream_t stream)
{
  (void)in_sizes; (void)n_in; (void)out_size; (void)ws_size;

  const float* tok  = (const float*)d_in[0];
  const float* supp = (const float*)d_in[1];
  const float* qry  = (const float*)d_in[2];
  const float* W_qa = (const float*)d_in[3];
  const float* b_qa = (const float*)d_in[4];
  const float* W_ks = (const float*)d_in[5];
  const float* b_ks = (const float*)d_in[6];
  const float* W_ka = (const float*)d_in[7];
  const float* b_ka = (const float*)d_in[8];
  const float* W_vs = (const float*)d_in[9];
  const float* b_vs = (const float*)d_in[10];
  const float* W_f1 = (const float*)d_in[11];
  const float* b_f1 = (const float*)d_in[12];
  const float* W_f2 = (const float*)d_in[13];
  const float* b_f2 = (const float*)d_in[14];

  char* W = (char*)d_ws;
  constexpr size_t MiB = 1048576;
  auto U = [&](size_t off) { return (unsigned short*)(W + off); };
  auto F = [&](size_t off) { return (float*)(W + off); };

  // interval-packed workspace (144 MiB total; baseline proved >=151 MB safe)
  const size_t O_IDXA = 0;                  // [9.6,12]
  const size_t O_IDXB = 65536;
  const size_t O_ACT0 = 0;                  // qry3/supp3 plane0
  const size_t O_ACT1 = 16 * MiB;           // plane1   (later vsT)
  const size_t O_ACT2 = 32 * MiB;           // plane2   (later sa_pl, dec)
  const size_t O_VST  = 16 * MiB;
  const size_t O_SAP0 = 32 * MiB;
  const size_t O_SAP1 = 40 * MiB;
  const size_t O_DEC  = 32 * MiB;
  const size_t O_QQ0  = 48 * MiB;           // qq3/ks3 planes
  const size_t O_QQ1  = 64 * MiB;
  const size_t O_QQ2  = 80 * MiB;
  const size_t O_LG   = 48 * MiB;           // 64 MiB [48,112)
  const size_t O_MID  = 48 * MiB;
  const size_t O_TOK0 = 96 * MiB;
  const size_t O_TOK1 = 100 * MiB;
  const size_t O_TOK2 = 104 * MiB;
  const size_t O_QTF  = 96 * MiB;
  const size_t O_WF1T = 96 * MiB;
  const size_t O_WF2T = 96 * MiB + 1536 * 1024;
  const size_t O_KA0  = 112 * MiB;
  const size_t O_KA1  = 116 * MiB;
  const size_t O_KA2  = 120 * MiB;
  const size_t O_SAF  = 112 * MiB;
  const size_t O_QTP0 = 112 * MiB;
  const size_t O_QTP1 = 120 * MiB;
  const size_t O_PT   = 112 * MiB;          // 32 MiB [112,144)
  const size_t O_WQAT = 124 * MiB;          // 3 planes x 512 KiB
  const size_t O_WKAT = 124 * MiB + 1536 * 1024;
  const size_t O_QA0  = 128 * MiB;
  const size_t O_QA1  = 132 * MiB;
  const size_t O_QA2  = 136 * MiB;
  const size_t O_WKST = 140 * MiB;
  const size_t O_WVST = 140 * MiB + 1536 * 1024;
  const size_t PW = 512 * 1024;             // one 512x512 bf16 plane

  const dim3 B256(256), BW(32, 8);

  // 1: tok-side splits
  split_wT<3><<<dim3(16,16), BW, 0, stream>>>(W_qa, U(O_WQAT), U(O_WQAT+PW), U(O_WQAT+2*PW), 512, 512);
  split_wT<3><<<dim3(16,16), BW, 0, stream>>>(W_ka, U(O_WKAT), U(O_WKAT+PW), U(O_WKAT+2*PW), 512, 512);
  split_act<3><<<dim3(2048), B256, 0, stream>>>((const f32x4*)tok, (u16x4*)U(O_TOK0), (u16x4*)U(O_TOK1), (u16x4*)U(O_TOK2), 524288);
  // 2: qa/ka projections (6-pass split): out 3-plane
  gmfma<6,4,true,false><<<dim3(32,4,1), B256, 0, stream>>>(
      U(O_TOK0),U(O_TOK1),U(O_TOK2), U(O_WQAT),U(O_WQAT+PW),U(O_WQAT+2*PW),
      b_qa, F(O_QA0), U(O_QA0),U(O_QA1),U(O_QA2), 512, 512, 0,0,0, 1.f);
  gmfma<6,4,true,false><<<dim3(32,4,1), B256, 0, stream>>>(
      U(O_TOK0),U(O_TOK1),U(O_TOK2), U(O_WKAT),U(O_WKAT+PW),U(O_WKAT+2*PW),
      b_ka, F(O_KA0), U(O_KA0),U(O_KA1),U(O_KA2), 512, 512, 0,0,0, 1.f);
  // 3: qry split
  split_act<3><<<dim3(8192), B256, 0, stream>>>((const f32x4*)qry, (u16x4*)U(O_ACT0), (u16x4*)U(O_ACT1), (u16x4*)U(O_ACT2), 2097152);
  // 4: qq projection
  gmfma<6,4,true,false><<<dim3(128,4,1), B256, 0, stream>>>(
      U(O_ACT0),U(O_ACT1),U(O_ACT2), U(O_WQAT),U(O_WQAT+PW),U(O_WQAT+2*PW),
      b_qa, F(O_QQ0), U(O_QQ0),U(O_QQ1),U(O_QQ2), 512, 512, 0,0,0, 1.f);
  // 5: scores_qt = qq . ka^T / 8  (fp32 out only)
  gmfma<6,0,false,false><<<dim3(8,2,16), B256, 0, stream>>>(
      U(O_QQ0),U(O_QQ1),U(O_QQ2), U(O_KA0),U(O_KA1),U(O_KA2),
      nullptr, F(O_QTF), U(O_QTF),U(O_QTF),U(O_QTF), 512, 256,
      524288, 131072, 262144, 0.125f);
  // 6: supp split + W_ks split
  split_act<3><<<dim3(8192), B256, 0, stream>>>((const f32x4*)supp, (u16x4*)U(O_ACT0), (u16x4*)U(O_ACT1), (u16x4*)U(O_ACT2), 2097152);
  split_wT<3><<<dim3(16,16), BW, 0, stream>>>(W_ks, U(O_WKST), U(O_WKST+PW), U(O_WKST+2*PW), 512, 512);
  // 7: ks projection
  gmfma<6,4,true,false><<<dim3(128,4,1), B256, 0, stream>>>(
      U(O_ACT0),U(O_ACT1),U(O_ACT2), U(O_WKST),U(O_WKST+PW),U(O_WKST+2*PW),
      b_ks, F(O_QQ0), U(O_QQ0),U(O_QQ1),U(O_QQ2), 512, 512, 0,0,0, 1.f);
  // 8.5: W_vs split
  split_wT<1><<<dim3(16,16), BW, 0, stream>>>(W_vs, U(O_WVST), U(O_WVST), U(O_WVST), 512, 512);
  // 9: scores_sa = ks . qa^T / 8  (fp32 + 2 planes)
  gmfma<6,3,false,false><<<dim3(8,2,16), B256, 0, stream>>>(
      U(O_QQ0),U(O_QQ1),U(O_QQ2), U(O_QA0),U(O_QA1),U(O_QA2),
      nullptr, F(O_SAF), U(O_SAP0),U(O_SAP1),U(O_SAP1), 512, 256,
      524288, 131072, 262144, 0.125f);
  // 9.3: vs projection -> vs^T bf16 (transposed epilogue), plain bf16
  gmfma<1,2,true,false><<<dim3(8,4,16), B256, 0, stream>>>(
      U(O_ACT0),U(O_ACT0),U(O_ACT0), U(O_WVST),U(O_WVST),U(O_WVST),
      b_vs, F(O_VST), U(O_VST),U(O_VST),U(O_VST), 512, 1024,
      524288, 0, 524288, 1.f);
  // 9.6: argmaxes
  row_argmax<<<dim3(kBS * kHW), dim3(64), 0, stream>>>(F(O_SAF), (int*)(W + O_IDXA));
  row_argmax<<<dim3(kBS * kHW), dim3(64), 0, stream>>>(F(O_QTF), (int*)(W + O_IDXB));
  // 10.7: split qt scores into 2 bf16 planes for logits
  split_act<2><<<dim3(4096), B256, 0, stream>>>((const f32x4*)F(O_QTF), (u16x4*)U(O_QTP0), (u16x4*)U(O_QTP1), (u16x4*)U(O_QTP1), 1048576);
  // 11: logits = sa . qt^T (2-split, 3-pass)
  gmfma<3,0,false,false><<<dim3(8,8,16), B256, 0, stream>>>(
      U(O_SAP0),U(O_SAP1),U(O_SAP1), U(O_QTP0),U(O_QTP1),U(O_QTP1),
      nullptr, F(O_LG), U(O_SAP0),U(O_SAP0),U(O_SAP0), 256, 1024,
      262144, 262144, 1048576, 1.f);
  // 12: masked softmax -> P^T bf16
  softmax_T<<<dim3(64,16), B256, 0, stream>>>(F(O_LG), (int*)(W + O_IDXA), (int*)(W + O_IDXB), U(O_PT));
  // 12.5: FFN weight splits (regions free now)
  split_wT<1><<<dim3(16,48), BW, 0, stream>>>(W_f1, U(O_WF1T), U(O_WF1T), U(O_WF1T), 512, 1536);
  split_wT<1><<<dim3(48,16), BW, 0, stream>>>(W_f2, U(O_WF2T), U(O_WF2T), U(O_WF2T), 1536, 512);
  // 13: dec = P^T . vs  (A=PT [j][i], B=vsT [c][i])
  gmfma<1,1,false,false><<<dim3(8,4,16), B256, 0, stream>>>(
      U(O_PT),U(O_PT),U(O_PT), U(O_VST),U(O_VST),U(O_VST),
      nullptr, F(O_DEC), U(O_DEC),U(O_DEC),U(O_DEC), 1024, 512,
      1048576, 524288, 524288, 1.f);
  // 14: FFN1 = relu(dec @ W_f1 + b1) -> bf16
  gmfma<1,1,true,true><<<dim3(128,12,1), B256, 0, stream>>>(
      U(O_DEC),U(O_DEC),U(O_DEC), U(O_WF1T),U(O_WF1T),U(O_WF1T),
      b_f1, F(O_MID), U(O_MID),U(O_MID),U(O_MID), 512, 1536, 0,0,0, 1.f);
  // 15: FFN2 = mid @ W_f2 + b2 -> d_out fp32
  gmfma<1,0,true,false><<<dim3(128,4,1), B256, 0, stream>>>(
      U(O_MID),U(O_MID),U(O_MID), U(O_WF2T),U(O_WF2T),U(O_WF2T),
      b_f2, (float*)d_out, U(O_MID),U(O_MID),U(O_MID), 1536, 512, 0,0,0, 1.f);
}

// Round 4
// 504.364 us; speedup vs baseline: 3.1662x; 1.4525x over previous
//
#include <hip/hip_runtime.h>

typedef float          f32x4  __attribute__((ext_vector_type(4)));
typedef short          bf16x8 __attribute__((ext_vector_type(8)));
typedef unsigned short u16x4  __attribute__((ext_vector_type(4)));

static constexpr int kBS = 16;
static constexpr int kHW = 1024;

__device__ __forceinline__ unsigned short f2bf(float x) {
  union { float f; unsigned int u; } v; v.f = x;
  unsigned int r = v.u + 0x7fffu + ((v.u >> 16) & 1u);
  return (unsigned short)(r >> 16);
}
__device__ __forceinline__ float bf2f(unsigned short h) {
  union { unsigned int u; float f; } v; v.u = ((unsigned int)h) << 16;
  return v.f;
}

// ---------------------------------------------------------------------------
// split kernels: fp32 -> NP bf16 planes (a = a0 + a1 [+ a2] RNE residuals)
// ---------------------------------------------------------------------------
template<int NP>
__global__ __launch_bounds__(256)
void split_act(const f32x4* __restrict__ X, u16x4* __restrict__ P0,
               u16x4* __restrict__ P1, u16x4* __restrict__ P2, int n4)
{
  int i = blockIdx.x * 256 + threadIdx.x;
  if (i >= n4) return;
  f32x4 x = X[i];
  u16x4 s0, s1, s2;
#pragma unroll
  for (int u = 0; u < 4; ++u) {
    unsigned short h0 = f2bf(x[u]); float r1 = x[u] - bf2f(h0);
    unsigned short h1 = f2bf(r1);
    s0[u] = h0; s1[u] = h1;
    if (NP == 3) s2[u] = f2bf(r1 - bf2f(h1));
  }
  P0[i] = s0;
  if (NP >= 2) P1[i] = s1;
  if (NP == 3) P2[i] = s2;
}

// W [K][N] fp32 -> NP bf16 planes of W^T [N][K]
template<int NP>
__global__ __launch_bounds__(256)
void split_wT(const float* __restrict__ Wm, unsigned short* __restrict__ T0,
              unsigned short* __restrict__ T1, unsigned short* __restrict__ T2,
              int K, int N)
{
  __shared__ float ts[32][33];
  const int k0 = blockIdx.x * 32, n0 = blockIdx.y * 32;
  const int tx = threadIdx.x, ty = threadIdx.y;   // 32 x 8
#pragma unroll
  for (int r = 0; r < 4; ++r)
    ts[ty + r * 8][tx] = Wm[(size_t)(k0 + ty + r * 8) * N + n0 + tx];
  __syncthreads();
#pragma unroll
  for (int r = 0; r < 4; ++r) {
    const int n = ty + r * 8;
    const float x = ts[tx][n];
    const size_t off = (size_t)(n0 + n) * K + k0 + tx;
    unsigned short h0 = f2bf(x); float r1 = x - bf2f(h0);
    unsigned short h1 = f2bf(r1);
    T0[off] = h0;
    if (NP >= 2) T1[off] = h1;
    if (NP == 3) T2[off] = f2bf(r1 - bf2f(h1));
  }
}

// ---------------------------------------------------------------------------
// Shared staging helper: one 128x32 bf16 tile, global (pre-swizzled cols) ->
// linear LDS via global_load_lds(16B). Per wave: 2 loads.
// ---------------------------------------------------------------------------
__device__ __forceinline__ void stage_tile(const unsigned short* src, int K,
                                           unsigned short* ldst, int wv, int lane)
{
#pragma unroll
  for (int i = 0; i < 2; ++i) {
    const int s   = wv * 128 + i * 64 + lane;
    const int row = s >> 2;
    const int gc  = ((s & 3) ^ ((row >> 1) & 3)) * 8;   // involution pre-swizzle
    __builtin_amdgcn_global_load_lds(
        (const __attribute__((address_space(1))) void*)(src + (size_t)row * K + gc),
        (__attribute__((address_space(3))) void*)(ldst + ((wv * 128 + i * 64) << 3)),
        16, 0, 0);
  }
}

// ---------------------------------------------------------------------------
// FUSED multi-plane MFMA GEMM. 128x128 tile, 4 waves, BK=32, single-buffer LDS
// holding all planes of the K-tile; 2 barriers + (MODE*16) MFMA per K-tile.
// MODE 6: 3-plane x 3-plane, pairs {00,01,02,10,11,20}  (fp32-accurate)
// MODE 3: 2-plane x 2-plane, pairs {00,01,10}
// A planes [M][K] bf16; B planes [N][K] bf16.
// OUTM: 0 = f32; 3 = f32 + 2 bf16 planes; 4 = 3 bf16 planes.
// ---------------------------------------------------------------------------
template<int MODE, int OUTM, bool BIAS>
__global__ __launch_bounds__(256)
void gmp(const unsigned short* __restrict__ A0, const unsigned short* __restrict__ A1,
         const unsigned short* __restrict__ A2,
         const unsigned short* __restrict__ B0, const unsigned short* __restrict__ B1,
         const unsigned short* __restrict__ B2,
         const float* __restrict__ bias,
         float* __restrict__ Cf, unsigned short* __restrict__ O0,
         unsigned short* __restrict__ O1, unsigned short* __restrict__ O2,
         int K, int ldc, long sA, long sB, long sC, float scale)
{
  constexpr int NPA = (MODE == 6) ? 3 : 2;
  constexpr int NT  = 2 * NPA;
  __shared__ alignas(16) unsigned short lds[NT * 4096];

  const int tid  = threadIdx.x;
  const int wv   = tid >> 6, lane = tid & 63;
  const int wr   = wv >> 1,  wc   = wv & 1;
  const int cr   = lane & 15, cg  = lane >> 4;
  const int bm   = blockIdx.x * 128, bn = blockIdx.y * 128;

  const size_t zA = (size_t)blockIdx.z * (size_t)sA;
  const size_t zB = (size_t)blockIdx.z * (size_t)sB;
  const size_t zC = (size_t)blockIdx.z * (size_t)sC;

  const unsigned short* srcs[NT];
  srcs[0] = A0 + zA + (size_t)bm * K;
  srcs[1] = A1 + zA + (size_t)bm * K;
  if (NPA == 3) srcs[2] = A2 + zA + (size_t)bm * K;
  srcs[NPA + 0] = B0 + zB + (size_t)bn * K;
  srcs[NPA + 1] = B1 + zB + (size_t)bn * K;
  if (NPA == 3) srcs[NPA + 2] = B2 + zB + (size_t)bn * K;

  f32x4 acc[4][4];
#pragma unroll
  for (int i = 0; i < 4; ++i)
#pragma unroll
    for (int j = 0; j < 4; ++j) {
      acc[i][j][0] = 0.f; acc[i][j][1] = 0.f; acc[i][j][2] = 0.f; acc[i][j][3] = 0.f;
    }

#define LOADA(pa)                                                               \
  {                                                                             \
    _Pragma("unroll")                                                           \
    for (int f = 0; f < 4; ++f) {                                               \
      const int ra = wr * 64 + f * 16 + cr;                                     \
      af[f] = *(const bf16x8*)&lds[(pa) * 4096 + (ra * 4 + (cg ^ ((ra >> 1) & 3))) * 8]; \
    }                                                                           \
  }
#define DOPB(pb)                                                                \
  {                                                                             \
    bf16x8 bf[4];                                                               \
    _Pragma("unroll")                                                           \
    for (int f = 0; f < 4; ++f) {                                               \
      const int rb = wc * 64 + f * 16 + cr;                                     \
      bf[f] = *(const bf16x8*)&lds[(NPA + (pb)) * 4096 + (rb * 4 + (cg ^ ((rb >> 1) & 3))) * 8]; \
    }                                                                           \
    _Pragma("unroll")                                                           \
    for (int i = 0; i < 4; ++i)                                                 \
      _Pragma("unroll")                                                         \
      for (int j = 0; j < 4; ++j)                                               \
        acc[i][j] = __builtin_amdgcn_mfma_f32_16x16x32_bf16(af[i], bf[j], acc[i][j], 0, 0, 0); \
  }

  const int nt = K >> 5;
  for (int kt = 0; kt < nt; ++kt) {
    if (kt) __syncthreads();             // readers of prev tile done
#pragma unroll
    for (int t = 0; t < NT; ++t)
      stage_tile(srcs[t] + kt * 32, K, &lds[t * 4096], wv, lane);
    __syncthreads();                     // implicit vmcnt(0): staging landed
    bf16x8 af[4];
    if (MODE == 6) {
      LOADA(0); DOPB(0); DOPB(1); DOPB(2);
      LOADA(1); DOPB(0); DOPB(1);
      LOADA(2); DOPB(0);
    } else {
      LOADA(0); DOPB(0); DOPB(1);
      LOADA(1); DOPB(0);
    }
  }
#undef LOADA
#undef DOPB

  float* CfB = Cf + zC;
  unsigned short* O0B = O0 + zC;
  unsigned short* O1B = O1 + zC;
  unsigned short* O2B = O2 + zC;
#pragma unroll
  for (int fm = 0; fm < 4; ++fm) {
#pragma unroll
    for (int fn = 0; fn < 4; ++fn) {
      const int n  = bn + wc * 64 + fn * 16 + cr;
      const int m0 = bm + wr * 64 + fm * 16 + 4 * cg;
      float bv = 0.f;
      if (BIAS) bv = bias[n];
      f32x4 v = acc[fm][fn];
#pragma unroll
      for (int r = 0; r < 4; ++r) {
        float x = v[r] * scale + bv;
        const size_t off = (size_t)(m0 + r) * ldc + n;
        if (OUTM == 0) CfB[off] = x;
        else {
          unsigned short h0 = f2bf(x); float r1 = x - bf2f(h0);
          unsigned short h1 = f2bf(r1);
          O0B[off] = h0; O1B[off] = h1;
          if (OUTM == 4) O2B[off] = f2bf(r1 - bf2f(h1));
          if (OUTM == 3) CfB[off] = x;
        }
      }
    }
  }
}

// ---------------------------------------------------------------------------
// Single-pass MFMA GEMM (known-good round-2 kernel), dbuf, BK=32.
// OUTM: 0=f32, 1=bf16, 2=bf16 transposed ([N][M], ldc=M).
// ---------------------------------------------------------------------------
template<int OUTM, bool BIAS, bool RELU>
__global__ __launch_bounds__(256)
void gmfma(const unsigned short* __restrict__ A0, const unsigned short* __restrict__ B0,
           const float* __restrict__ bias,
           float* __restrict__ Cf, unsigned short* __restrict__ O0,
           int K, int ldc, long sA, long sB, long sC, float scale)
{
  __shared__ alignas(16) unsigned short lsA[2][4096];
  __shared__ alignas(16) unsigned short lsB[2][4096];

  const int tid  = threadIdx.x;
  const int wv   = tid >> 6, lane = tid & 63;
  const int wr   = wv >> 1,  wc   = wv & 1;
  const int cr   = lane & 15, cg  = lane >> 4;
  const int bm   = blockIdx.x * 128, bn = blockIdx.y * 128;

  const unsigned short* Ap = A0 + (size_t)blockIdx.z * (size_t)sA + (size_t)bm * K;
  const unsigned short* Bp = B0 + (size_t)blockIdx.z * (size_t)sB + (size_t)bn * K;
  const size_t zC = (size_t)blockIdx.z * (size_t)sC;

  f32x4 acc[4][4];
#pragma unroll
  for (int i = 0; i < 4; ++i)
#pragma unroll
    for (int j = 0; j < 4; ++j) {
      acc[i][j][0] = 0.f; acc[i][j][1] = 0.f; acc[i][j][2] = 0.f; acc[i][j][3] = 0.f;
    }

  const int nt = K >> 5;
  stage_tile(Ap, K, lsA[0], wv, lane);
  stage_tile(Bp, K, lsB[0], wv, lane);
  for (int t = 0; t < nt; ++t) {
    __syncthreads();
    const int tn = t + 1;
    if (tn < nt) {
      stage_tile(Ap + tn * 32, K, lsA[tn & 1], wv, lane);
      stage_tile(Bp + tn * 32, K, lsB[tn & 1], wv, lane);
    }
    const unsigned short* lA = lsA[t & 1];
    const unsigned short* lB = lsB[t & 1];
    bf16x8 af[4], bf[4];
#pragma unroll
    for (int f = 0; f < 4; ++f) {
      const int ra = wr * 64 + f * 16 + cr;
      af[f] = *(const bf16x8*)&lA[(ra * 4 + (cg ^ ((ra >> 1) & 3))) * 8];
      const int rb = wc * 64 + f * 16 + cr;
      bf[f] = *(const bf16x8*)&lB[(rb * 4 + (cg ^ ((rb >> 1) & 3))) * 8];
    }
#pragma unroll
    for (int i = 0; i < 4; ++i)
#pragma unroll
      for (int j = 0; j < 4; ++j)
        acc[i][j] = __builtin_amdgcn_mfma_f32_16x16x32_bf16(af[i], bf[j], acc[i][j], 0, 0, 0);
  }

  float* CfB = Cf + zC;
  unsigned short* O0B = O0 + zC;
#pragma unroll
  for (int fm = 0; fm < 4; ++fm) {
#pragma unroll
    for (int fn = 0; fn < 4; ++fn) {
      const int n  = bn + wc * 64 + fn * 16 + cr;
      const int m0 = bm + wr * 64 + fm * 16 + 4 * cg;
      float bv = 0.f;
      if (BIAS) bv = bias[n];
      f32x4 v = acc[fm][fn];
      if (OUTM == 2) {
        u16x4 o;
#pragma unroll
        for (int r = 0; r < 4; ++r) {
          float x = v[r] * scale + bv;
          if (RELU) x = fmaxf(x, 0.f);
          o[r] = f2bf(x);
        }
        *(u16x4*)(O0B + (size_t)n * ldc + m0) = o;
      } else {
#pragma unroll
        for (int r = 0; r < 4; ++r) {
          float x = v[r] * scale + bv;
          if (RELU) x = fmaxf(x, 0.f);
          const size_t off = (size_t)(m0 + r) * ldc + n;
          if (OUTM == 0) CfB[off] = x;
          else O0B[off] = f2bf(x);
        }
      }
    }
  }
}

// ---------------------------------------------------------------------------
// Row argmax over rows of length 256 (np.argmax first-max tie rule).
// ---------------------------------------------------------------------------
__global__ __launch_bounds__(64)
void row_argmax(const float* __restrict__ X, int* __restrict__ out)
{
  const int row = blockIdx.x;
  const float* xr = X + (size_t)row * 256;
  const int lane = threadIdx.x;
  float best = -3.0e38f;
  int bi = 0;
#pragma unroll
  for (int t = 0; t < 4; ++t) {
    const int a = lane + (t << 6);
    const float x = xr[a];
    if (x > best) { best = x; bi = a; }
  }
#pragma unroll
  for (int off = 32; off >= 1; off >>= 1) {
    const float ov = __shfl_xor(best, off);
    const int   oi = __shfl_xor(bi, off);
    if (ov > best || (ov == best && oi < bi)) { best = ov; bi = oi; }
  }
  if (lane == 0) out[row] = bi;
}

// ---------------------------------------------------------------------------
// Masked softmax over rows of length 1024 for a 512-row i-half; emits
// P^T[b][j][i_global] bf16. Lg layout [b][512][1024].
// ---------------------------------------------------------------------------
__global__ __launch_bounds__(256)
void softmax_T(const float* __restrict__ Lg, const int* __restrict__ aidx,
               const int* __restrict__ bidx, unsigned short* __restrict__ PT,
               int ihalf)
{
  __shared__ int bj[1024];
  __shared__ unsigned short tile[1024 * 17];
  const int tid = threadIdx.x;
  const int i0  = blockIdx.x * 16;          // 0..511
  const int b   = blockIdx.y;
  const int r   = tid >> 4;
  const int l16 = tid & 15;

  for (int j = tid; j < 1024; j += 256) bj[j] = bidx[(b << 10) + j];
  __syncthreads();

  const int ai  = aidx[(b << 10) + (ihalf << 9) + i0 + r];
  const float* Lr = Lg + ((size_t)b * 512 + i0 + r) * 1024;
  const int jb = l16 * 64;

  float x[64];
  float mx = -3.0e38f;
#pragma unroll
  for (int q = 0; q < 16; ++q) {
    f32x4 f = *(const f32x4*)(Lr + jb + (q << 2));
#pragma unroll
    for (int u = 0; u < 4; ++u) {
      const int j = jb + (q << 2) + u;
      float t = f[u];
      if (bj[j] != ai) t -= 1e6f;
      x[(q << 2) + u] = t;
      mx = fmaxf(mx, t);
    }
  }
#pragma unroll
  for (int off = 8; off >= 1; off >>= 1) mx = fmaxf(mx, __shfl_xor(mx, off));
  float s = 0.f;
#pragma unroll
  for (int k = 0; k < 64; ++k) { float e = expf(x[k] - mx); x[k] = e; s += e; }
#pragma unroll
  for (int off = 8; off >= 1; off >>= 1) s += __shfl_xor(s, off);
  const float inv = 1.f / s;

#pragma unroll
  for (int k = 0; k < 64; ++k)
    tile[(jb + k) * 17 + r] = f2bf(x[k] * inv);
  __syncthreads();

  for (int j = tid; j < 1024; j += 256) {
    const unsigned short* tp = &tile[j * 17];
    unsigned int w[8];
#pragma unroll
    for (int q = 0; q < 8; ++q)
      w[q] = (unsigned int)tp[2 * q] | ((unsigned int)tp[2 * q + 1] << 16);
    const size_t off = ((size_t)b << 20) + ((size_t)j << 10) + (ihalf << 9) + i0;
    unsigned int* dst = (unsigned int*)(PT + off);
    *(uint4*)dst       = make_uint4(w[0], w[1], w[2], w[3]);
    *((uint4*)dst + 1) = make_uint4(w[4], w[5], w[6], w[7]);
  }
}

// ---------------------------------------------------------------------------
extern "C" void kernel_launch(void* const* d_in, const int* in_sizes, int n_in,
                              void* d_out, int out_size, void* d_ws, size_t ws_size,
                              hipStream_t stream)
{
  (void)in_sizes; (void)n_in; (void)out_size; (void)ws_size;

  const float* tok  = (const float*)d_in[0];
  const float* supp = (const float*)d_in[1];
  const float* qry  = (const float*)d_in[2];
  const float* W_qa = (const float*)d_in[3];
  const float* b_qa = (const float*)d_in[4];
  const float* W_ks = (const float*)d_in[5];
  const float* b_ks = (const float*)d_in[6];
  const float* W_ka = (const float*)d_in[7];
  const float* b_ka = (const float*)d_in[8];
  const float* W_vs = (const float*)d_in[9];
  const float* b_vs = (const float*)d_in[10];
  const float* W_f1 = (const float*)d_in[11];
  const float* b_f1 = (const float*)d_in[12];
  const float* W_f2 = (const float*)d_in[13];
  const float* b_f2 = (const float*)d_in[14];

  char* W = (char*)d_ws;
  constexpr size_t MiB = 1048576;
  auto U = [&](double off) { return (unsigned short*)(W + (size_t)(off * MiB)); };
  auto F = [&](double off) { return (float*)(W + (size_t)(off * MiB)); };
  auto I = [&](double off) { return (int*)(W + (size_t)(off * MiB)); };

  // lifetimes (MiB): @0 tokP[0,4,8] -> QTF -> suppP0 -> SAF -> PT(0-32)
  // @16 WQAT,17.5 WKAT,19 WKST,20.5 WVST | @22 qaP, @34 kaP (later dec@32-48)
  // @46 qryP[46,62,78] -> QTP[46,54] | suppP1@62,suppP2@78 -> vsT@62, SAP@78,86
  // @94 qqP[94,110,126] -> ksP -> Lg(94-126) | mid@62-110 | WF@142 | idx@150
  const double oTOK0=0, oTOK1=4, oTOK2=8, oQTF=0, oSUP0=0, oSAF=0, oPT=0;
  const double oWQAT=16, oWKAT=17.5, oWKST=19, oWVST=20.5;
  const double oQA0=22, oQA1=26, oQA2=30, oDEC=32, oKA0=34, oKA1=38, oKA2=42;
  const double oQRY0=46, oQRY1=62, oQRY2=78, oQTP0=46, oQTP1=54;
  const double oSUP1=62, oSUP2=78, oVST=62, oSAP0=78, oSAP1=86;
  const double oQQ0=94, oQQ1=110, oQQ2=126, oLG=94, oMID=62;
  const double oWF1=142, oWF2=143.5, oIDXB=150, oIDXA=150.0625;
  const double hP = 0.5;  // 512x512 bf16 plane = 0.5 MiB

  const dim3 B256(256), BW(32, 8);
  float* dummyF = F(oLG);
  unsigned short* dummyU = U(oLG);

  // S1: splits
  split_wT<3><<<dim3(16,16), BW, 0, stream>>>(W_qa, U(oWQAT), U(oWQAT+hP), U(oWQAT+2*hP), 512, 512);
  split_wT<3><<<dim3(16,16), BW, 0, stream>>>(W_ka, U(oWKAT), U(oWKAT+hP), U(oWKAT+2*hP), 512, 512);
  split_wT<3><<<dim3(16,16), BW, 0, stream>>>(W_ks, U(oWKST), U(oWKST+hP), U(oWKST+2*hP), 512, 512);
  split_wT<1><<<dim3(16,16), BW, 0, stream>>>(W_vs, U(oWVST), nullptr, nullptr, 512, 512);
  split_act<3><<<dim3(2048), B256, 0, stream>>>((const f32x4*)tok, (u16x4*)U(oTOK0), (u16x4*)U(oTOK1), (u16x4*)U(oTOK2), 524288);
  // S2: qa, ka projections (fused 6-pass, 3-plane out)
  gmp<6,4,true><<<dim3(32,4,1), B256, 0, stream>>>(
      U(oTOK0),U(oTOK1),U(oTOK2), U(oWQAT),U(oWQAT+hP),U(oWQAT+2*hP),
      b_qa, dummyF, U(oQA0),U(oQA1),U(oQA2), 512, 512, 0,0,0, 1.f);
  gmp<6,4,true><<<dim3(32,4,1), B256, 0, stream>>>(
      U(oTOK0),U(oTOK1),U(oTOK2), U(oWKAT),U(oWKAT+hP),U(oWKAT+2*hP),
      b_ka, dummyF, U(oKA0),U(oKA1),U(oKA2), 512, 512, 0,0,0, 1.f);
  // S3: qry split
  split_act<3><<<dim3(8192), B256, 0, stream>>>((const f32x4*)qry, (u16x4*)U(oQRY0), (u16x4*)U(oQRY1), (u16x4*)U(oQRY2), 2097152);
  // S4: qq projection
  gmp<6,4,true><<<dim3(128,4,1), B256, 0, stream>>>(
      U(oQRY0),U(oQRY1),U(oQRY2), U(oWQAT),U(oWQAT+hP),U(oWQAT+2*hP),
      b_qa, dummyF, U(oQQ0),U(oQQ1),U(oQQ2), 512, 512, 0,0,0, 1.f);
  // S5: qt score = qq . ka^T / 8  -> f32 + 2 planes (split folded in)
  gmp<6,3,false><<<dim3(8,2,16), B256, 0, stream>>>(
      U(oQQ0),U(oQQ1),U(oQQ2), U(oKA0),U(oKA1),U(oKA2),
      nullptr, F(oQTF), U(oQTP0),U(oQTP1),dummyU, 512, 256,
      524288, 131072, 262144, 0.125f);
  row_argmax<<<dim3(kBS * kHW), dim3(64), 0, stream>>>(F(oQTF), I(oIDXB));
  // S6: supp split (plane0 over dead QTF region)
  split_act<3><<<dim3(8192), B256, 0, stream>>>((const f32x4*)supp, (u16x4*)U(oSUP0), (u16x4*)U(oSUP1), (u16x4*)U(oSUP2), 2097152);
  // S7: ks projection, then vs^T (reads only supp plane0)
  gmp<6,4,true><<<dim3(128,4,1), B256, 0, stream>>>(
      U(oSUP0),U(oSUP1),U(oSUP2), U(oWKST),U(oWKST+hP),U(oWKST+2*hP),
      b_ks, dummyF, U(oQQ0),U(oQQ1),U(oQQ2), 512, 512, 0,0,0, 1.f);
  gmfma<2,true,false><<<dim3(8,4,16), B256, 0, stream>>>(
      U(oSUP0), U(oWVST), b_vs, dummyF, U(oVST), 512, 1024,
      524288, 0, 524288, 1.f);
  // S8: sa score = ks . qa^T / 8
  gmp<6,3,false><<<dim3(8,2,16), B256, 0, stream>>>(
      U(oQQ0),U(oQQ1),U(oQQ2), U(oQA0),U(oQA1),U(oQA2),
      nullptr, F(oSAF), U(oSAP0),U(oSAP1),dummyU, 512, 256,
      524288, 131072, 262144, 0.125f);
  row_argmax<<<dim3(kBS * kHW), dim3(64), 0, stream>>>(F(oSAF), I(oIDXA));
  // FFN weight splits (regions stable through the end)
  split_wT<1><<<dim3(16,48), BW, 0, stream>>>(W_f1, U(oWF1), nullptr, nullptr, 512, 1536);
  split_wT<1><<<dim3(48,16), BW, 0, stream>>>(W_f2, U(oWF2), nullptr, nullptr, 1536, 512);
  // S9/S10: logits halves (2-plane fused, 3 passes) + masked softmax -> P^T
  for (int h = 0; h < 2; ++h) {
    gmp<3,0,false><<<dim3(4,8,16), B256, 0, stream>>>(
        U(oSAP0) + (size_t)h*512*256, U(oSAP1) + (size_t)h*512*256, dummyU,
        U(oQTP0), U(oQTP1), dummyU,
        nullptr, F(oLG), dummyU,dummyU,dummyU, 256, 1024,
        262144, 262144, 524288, 1.f);
    softmax_T<<<dim3(32,16), B256, 0, stream>>>(F(oLG), I(oIDXA), I(oIDXB), U(oPT), h);
  }
  // S11: dec = P^T . vs   (A=PT [j][i], B=vsT [c][i])
  gmfma<1,false,false><<<dim3(8,4,16), B256, 0, stream>>>(
      U(oPT), U(oVST), nullptr, dummyF, U(oDEC), 1024, 512,
      1048576, 524288, 524288, 1.f);
  // S12: FFN1 = relu(dec @ W_f1 + b1) -> bf16
  gmfma<1,true,true><<<dim3(128,12,1), B256, 0, stream>>>(
      U(oDEC), U(oWF1), b_f1, dummyF, U(oMID), 512, 1536, 0,0,0, 1.f);
  // S13: FFN2 = mid @ W_f2 + b2 -> d_out fp32
  gmfma<0,true,false><<<dim3(128,4,1), B256, 0, stream>>>(
      U(oMID), U(oWF2), b_f2, (float*)d_out, dummyU, 1536, 512, 0,0,0, 1.f);
}